// Round 13
// baseline (44.892 us; speedup 1.0000x reference)
//
#include <hip/hip_runtime.h>

#define NT 1024
#define NBLK 512             // 2 blocks/CU * 256 CU; 2048 threads/CU
#define NBUCK 1024
#define CNT_SHIFT 40
#define EXP_SCALE 2048.0f
#define EXP_MASK ((1ull << CNT_SHIFT) - 1)

static __device__ __forceinline__ float clip10(float x) {
    return fminf(10.0f, fmaxf(-10.0f, x));
}

// Pack one sample: (censor << 40) | round(exp(clip(lr)) * 2^11).
// Global bounds: cnt <= n = 8.4M < 2^24; exp-sum ~1.4e7*2048 ~= 2.9e10 << 2^40.
static __device__ __forceinline__ unsigned long long pack_sample(float lv, int cv, float* lsum) {
    float e = __expf(lv);
    unsigned long long pk = ((unsigned long long)(cv & 1) << CNT_SHIFT)
                          | (unsigned long long)(e * EXP_SCALE + 0.5f);
    if (cv == 1) *lsum += lv;
    return pk;
}

// Fused kernel: streaming LDS histogram + packed-u64 flush (round-10 body),
// then "last block done" finalize inline. No grid.sync, no spinning: blocks
// that are not last simply exit -- cannot deadlock under any scheduling.
__global__ __launch_bounds__(NT)
void cox_fused(const float* __restrict__ lr, const float* __restrict__ tm,
               const int* __restrict__ cen, unsigned long long* __restrict__ bucket,
               double* __restrict__ bsum, unsigned* __restrict__ done,
               float* __restrict__ out, int n) {
    __shared__ unsigned long long h[NBUCK];
    __shared__ double swave[NT / 64];
    __shared__ float sh[NT];
    __shared__ double r1[NT / 64], r2[NT / 64], r3[NT / 64];
    __shared__ unsigned is_last;

    for (int idx = threadIdx.x; idx < NBUCK; idx += NT) h[idx] = 0ull;
    __syncthreads();

    // ---- streaming histogram (identical to round-10 pass1) ----
    const int n4 = n >> 2;
    const int stride = gridDim.x * NT;
    const float fB = (float)NBUCK;
    float lsum = 0.0f;

    int i = blockIdx.x * NT + threadIdx.x;
    for (; i + 3 * stride < n4; i += 4 * stride) {
        float4 l0 = ((const float4*)lr)[i];
        float4 l1 = ((const float4*)lr)[i + stride];
        float4 l2 = ((const float4*)lr)[i + 2 * stride];
        float4 l3 = ((const float4*)lr)[i + 3 * stride];
        float4 t0 = ((const float4*)tm)[i];
        float4 t1 = ((const float4*)tm)[i + stride];
        float4 t2 = ((const float4*)tm)[i + 2 * stride];
        float4 t3 = ((const float4*)tm)[i + 3 * stride];
        int4  c0 = ((const int4*)cen)[i];
        int4  c1 = ((const int4*)cen)[i + stride];
        int4  c2 = ((const int4*)cen)[i + 2 * stride];
        int4  c3 = ((const int4*)cen)[i + 3 * stride];
        const float4* ls[4] = {&l0, &l1, &l2, &l3};
        const float4* ts[4] = {&t0, &t1, &t2, &t3};
        const int4*   cs[4] = {&c0, &c1, &c2, &c3};
        #pragma unroll
        for (int g = 0; g < 4; ++g) {
            #pragma unroll
            for (int j = 0; j < 4; ++j) {
                float lv = clip10(((const float*)ls[g])[j]);
                float tv = ((const float*)ts[g])[j];
                int   cv = ((const int*)cs[g])[j];
                unsigned b = (unsigned)(tv * fB);
                if (b >= NBUCK) b = NBUCK - 1;
                atomicAdd(&h[b], pack_sample(lv, cv, &lsum));   // ds_add_u64
            }
        }
    }
    for (; i < n4; i += stride) {
        float4 l = ((const float4*)lr)[i];
        float4 t = ((const float4*)tm)[i];
        int4  cz = ((const int4*)cen)[i];
        #pragma unroll
        for (int j = 0; j < 4; ++j) {
            float lv = clip10(((const float*)&l)[j]);
            float tv = ((const float*)&t)[j];
            int   cv = ((const int*)&cz)[j];
            unsigned b = (unsigned)(tv * fB);
            if (b >= NBUCK) b = NBUCK - 1;
            atomicAdd(&h[b], pack_sample(lv, cv, &lsum));
        }
    }
    if (blockIdx.x == 0 && threadIdx.x == 0) {       // tail (n % 4 != 0)
        for (int k = n4 << 2; k < n; ++k) {
            float lv = clip10(lr[k]);
            unsigned b = (unsigned)(tm[k] * fB);
            if (b >= NBUCK) b = NBUCK - 1;
            atomicAdd(&h[b], pack_sample(lv, cen[k], &lsum));
        }
    }
    __syncthreads();

    // Flush: one packed u64 atomic per bucket (NT >= NBUCK: single op/thread).
    if (threadIdx.x < NBUCK)
        atomicAdd(&bucket[threadIdx.x], h[threadIdx.x]);

    // lr-sum: wave shuffle, fold wave partials -> one f64 atomic per block
    // into this block's own zeroed slot (distinct addresses; coherent).
    double d = (double)lsum;
    #pragma unroll
    for (int off = 32; off > 0; off >>= 1)
        d += __shfl_down(d, off, 64);
    if ((threadIdx.x & 63) == 0) swave[threadIdx.x >> 6] = d;
    __syncthreads();
    if (threadIdx.x == 0) {
        double acc = 0.0;
        #pragma unroll
        for (int w = 0; w < NT / 64; ++w) acc += swave[w];
        unsafeAtomicAdd(&bsum[blockIdx.x], acc);
    }

    // ---- arrival: barrier drains this block's outstanding atomics ----
    __syncthreads();
    if (threadIdx.x == 0) {
        __threadfence();
        unsigned prev = atomicAdd(done, 1u);
        is_last = (prev == gridDim.x - 1) ? 1u : 0u;
    }
    __syncthreads();
    if (!is_last) return;
    __threadfence();   // acquire: all blocks' flushes visible

    // ---- finalize (runs in the single last block) ----
    int t = threadIdx.x;
    unsigned long long pk = bucket[t];               // NT == NBUCK
    float v = (float)((double)(pk & EXP_MASK) * (1.0 / (double)EXP_SCALE));
    float c = (float)(unsigned)(pk >> CNT_SHIFT);

    sh[t] = v;
    __syncthreads();
    for (int dd = 1; dd < NT; dd <<= 1) {            // inclusive prefix sum
        float add = (t >= dd) ? sh[t - dd] : 0.0f;
        __syncthreads();
        sh[t] += add;
        __syncthreads();
    }
    float total = sh[NT - 1];
    float cum = total - sh[t] + v;                   // suffix-inclusive at t
    double dot = (double)(c * logf(cum + 1e-15f));
    double cs  = (double)c;
    double wacc = (t < NBLK) ? bsum[t] : 0.0;

    #pragma unroll
    for (int off = 32; off > 0; off >>= 1) {
        dot  += __shfl_down(dot, off, 64);
        cs   += __shfl_down(cs, off, 64);
        wacc += __shfl_down(wacc, off, 64);
    }
    if ((t & 63) == 0) { r1[t >> 6] = dot; r2[t >> 6] = cs; r3[t >> 6] = wacc; }
    __syncthreads();
    if (t == 0) {
        double sdot = 0.0, scs = 0.0, slr = 0.0;
        #pragma unroll
        for (int w = 0; w < NT / 64; ++w) { sdot += r1[w]; scs += r2[w]; slr += r3[w]; }
        double tot = slr - sdot;
        double denom = (scs < 1.0) ? 1.0 : scs;
        out[0] = (float)(-tot / denom);
    }
}

extern "C" void kernel_launch(void* const* d_in, const int* in_sizes, int n_in,
                              void* d_out, int out_size, void* d_ws, size_t ws_size,
                              hipStream_t stream) {
    const float* lr  = (const float*)d_in[0];
    const float* tm  = (const float*)d_in[1];
    const int*   cen = (const int*)d_in[2];
    float* out = (float*)d_out;
    int n = in_sizes[0];

    // Workspace layout: bucket[1024] u64 | bsum[512] f64 | done counter.
    unsigned long long* bucket = (unsigned long long*)d_ws;
    double*   bsum = (double*)(bucket + NBUCK);
    unsigned* done = (unsigned*)(bsum + NBLK);

    size_t zbytes = (size_t)NBUCK * 8 + (size_t)NBLK * 8 + 16;
    hipMemsetAsync(d_ws, 0, zbytes, stream);

    cox_fused<<<NBLK, NT, 0, stream>>>(lr, tm, cen, bucket, bsum, done, out, n);
}

// Round 14
// 33.366 us; speedup vs baseline: 1.3454x; 1.3454x over previous
//
#include <hip/hip_runtime.h>

#define NT 1024
#define NBLK 512             // 2 blocks/CU * 256 CU; 2048 threads/CU
#define NBUCK 1024
#define CNT_SHIFT 40
#define EXP_SCALE 2048.0f
#define EXP_MASK ((1ull << CNT_SHIFT) - 1)

static __device__ __forceinline__ float clip10(float x) {
    return fminf(10.0f, fmaxf(-10.0f, x));
}

// Process one sample: pack (censor << 40) | round(exp(clip(lr)) * 2^11) and
// ds_add_u64 it into the LDS histogram. Bounds: cnt <= 8.4M < 2^24;
// exp-sum ~1.4e7*2048 ~= 2.9e10 << 2^40.
#define PROC1(LV, TV, CV) do {                                              \
    float lv_ = clip10(LV);                                                 \
    float e_ = __expf(lv_);                                                 \
    unsigned b_ = (unsigned)((TV) * fB);                                    \
    if (b_ >= NBUCK) b_ = NBUCK - 1;                                        \
    unsigned long long pk_ = ((unsigned long long)((CV) & 1) << CNT_SHIFT)  \
                           | (unsigned long long)(e_ * EXP_SCALE + 0.5f);   \
    if ((CV) == 1) lsum += lv_;                                             \
    atomicAdd(&h[b_], pk_);                                                 \
} while (0)

#define PROC4(L, T, C) do {                                                 \
    PROC1((L).x, (T).x, (C).x); PROC1((L).y, (T).y, (C).y);                 \
    PROC1((L).z, (T).z, (C).z); PROC1((L).w, (T).w, (C).w);                 \
} while (0)

// Pass 1: streaming LDS histogram. Specialized flat path for the exact shape
// (4 float4-groups per thread): all 12 loads issued as named registers before
// any use -> compiler keeps them in flight (MLP 12), waits incrementally.
__global__ __launch_bounds__(NT, 4)
void cox_pass1(const float* __restrict__ lr, const float* __restrict__ tm,
               const int* __restrict__ cen, unsigned long long* __restrict__ bucket,
               double* __restrict__ bsum, int n) {
    __shared__ unsigned long long h[NBUCK];
    __shared__ double swave[NT / 64];
    for (int idx = threadIdx.x; idx < NBUCK; idx += NT) h[idx] = 0ull;
    __syncthreads();

    const int n4 = n >> 2;
    const int stride = gridDim.x * NT;
    const float fB = (float)NBUCK;
    float lsum = 0.0f;

    const float4* LR4 = (const float4*)lr;
    const float4* TM4 = (const float4*)tm;
    const int4*   CE4 = (const int4*)cen;

    int i = blockIdx.x * NT + threadIdx.x;
    if ((n & 3) == 0 && n4 == 4 * stride) {
        // Exact harness shape: every thread owns groups i, i+s, i+2s, i+3s.
        float4 l0 = LR4[i];
        float4 l1 = LR4[i + stride];
        float4 l2 = LR4[i + 2 * stride];
        float4 l3 = LR4[i + 3 * stride];
        float4 t0 = TM4[i];
        float4 t1 = TM4[i + stride];
        float4 t2 = TM4[i + 2 * stride];
        float4 t3 = TM4[i + 3 * stride];
        int4   c0 = CE4[i];
        int4   c1 = CE4[i + stride];
        int4   c2 = CE4[i + 2 * stride];
        int4   c3 = CE4[i + 3 * stride];
        PROC4(l0, t0, c0);
        PROC4(l1, t1, c1);
        PROC4(l2, t2, c2);
        PROC4(l3, t3, c3);
    } else {
        // Generic fallback: grid-stride over float4 groups.
        for (; i < n4; i += stride) {
            float4 l = LR4[i];
            float4 t = TM4[i];
            int4  cz = CE4[i];
            PROC4(l, t, cz);
        }
        if (blockIdx.x == 0 && threadIdx.x == 0) {   // tail (n % 4 != 0)
            for (int k = n4 << 2; k < n; ++k) {
                float tvk = tm[k];
                float lvk = lr[k];
                int   cvk = cen[k];
                PROC1(lvk, tvk, cvk);
            }
        }
    }
    __syncthreads();

    // Flush: one packed u64 atomic per bucket (NT >= NBUCK: one op/thread).
    if (threadIdx.x < NBUCK)
        atomicAdd(&bucket[threadIdx.x], h[threadIdx.x]);

    // lr-sum: wave shuffle, fold wave partials -> one double per block.
    double d = (double)lsum;
    #pragma unroll
    for (int off = 32; off > 0; off >>= 1)
        d += __shfl_down(d, off, 64);
    if ((threadIdx.x & 63) == 0) swave[threadIdx.x >> 6] = d;
    __syncthreads();
    if (threadIdx.x == 0) {
        double acc = 0.0;
        #pragma unroll
        for (int w = 0; w < NT / 64; ++w) acc += swave[w];
        bsum[blockIdx.x] = acc;
    }
}

// Pass 2: single block (256 threads). Unpack the 1024 packed buckets,
// suffix-inclusive scan of exp sums, dot = sum_b cnt_b*log(cum_b + 1e-15),
// fold per-block lr sums, then loss = -(sum_lr - dot)/n_events.
__global__ void cox_scanfinal(const unsigned long long* __restrict__ bucket,
                              const double* __restrict__ bsum, int nblk,
                              float* __restrict__ out) {
    int t = threadIdx.x;
    float v[4], c[4];
    float s = 0.0f;
    #pragma unroll
    for (int j = 0; j < 4; ++j) {
        unsigned long long pk = bucket[t * 4 + j];
        v[j] = (float)((double)(pk & EXP_MASK) * (1.0 / (double)EXP_SCALE));
        c[j] = (float)(unsigned)(pk >> CNT_SHIFT);
        s += v[j];
    }
    double wacc = 0.0;
    for (int k = t; k < nblk; k += 256) wacc += bsum[k];

    __shared__ float sh[256];
    sh[t] = s;
    __syncthreads();
    for (int d = 1; d < 256; d <<= 1) {
        float add = (t >= d) ? sh[t - d] : 0.0f;
        __syncthreads();
        sh[t] += add;
        __syncthreads();
    }
    float total = sh[255];
    float run = total - sh[t];          // sum over threads strictly after t
    double dot = 0.0;
    float cs = 0.0f;
    #pragma unroll
    for (int j = 3; j >= 0; --j) {
        run += v[j];                    // suffix-inclusive cum at bucket t*4+j
        dot += (double)(c[j] * logf(run + 1e-15f));
        cs  += c[j];
    }
    __shared__ double sdd[256];
    __shared__ double swl[256];
    __shared__ float scc[256];
    sdd[t] = dot; swl[t] = wacc; scc[t] = cs;
    __syncthreads();
    for (int d = 128; d > 0; d >>= 1) {
        if (t < d) { sdd[t] += sdd[t + d]; swl[t] += swl[t + d]; scc[t] += scc[t + d]; }
        __syncthreads();
    }
    if (t == 0) {
        double tot = swl[0] - sdd[0];
        double denom = (scc[0] < 1.0f) ? 1.0 : (double)scc[0];
        out[0] = (float)(-tot / denom);
    }
}

extern "C" void kernel_launch(void* const* d_in, const int* in_sizes, int n_in,
                              void* d_out, int out_size, void* d_ws, size_t ws_size,
                              hipStream_t stream) {
    const float* lr  = (const float*)d_in[0];
    const float* tm  = (const float*)d_in[1];
    const int*   cen = (const int*)d_in[2];
    float* out = (float*)d_out;
    int n = in_sizes[0];

    unsigned long long* bucket = (unsigned long long*)d_ws;
    double* bsum = (double*)(bucket + NBUCK);   // 8 KB offset, 8-aligned

    hipMemsetAsync(bucket, 0, (size_t)NBUCK * 8, stream);
    cox_pass1<<<NBLK, NT, 0, stream>>>(lr, tm, cen, bucket, bsum, n);
    cox_scanfinal<<<1, 256, 0, stream>>>(bucket, bsum, NBLK, out);
}